// Round 3
// baseline (701.231 us; speedup 1.0000x reference)
//
#include <hip/hip_runtime.h>

typedef unsigned short u16;
typedef float f4 __attribute__((ext_vector_type(4)));
typedef u16 u16x8 __attribute__((ext_vector_type(8)));

// ---------- bf16 helpers ----------
static __device__ __forceinline__ float bf2f(u16 u) {
    union { unsigned int i; float f; } v;
    v.i = ((unsigned int)u) << 16;
    return v.f;
}
static __device__ __forceinline__ u16 f2bf(float f) {
    union { float f; unsigned int i; } v;
    v.f = f;
    unsigned int x = v.i;
    x += 0x7fffu + ((x >> 16) & 1u);   // RNE
    return (u16)(x >> 16);
}
// dtype-flexible load: dt==0 -> bf16, dt==1 -> f32
static __device__ __forceinline__ float gld(int dt, const void* p, int i) {
    return dt ? ((const float*)p)[i] : bf2f(((const u16*)p)[i]);
}

// ---------- ws layout (bytes) ----------
#define FLAG_OFF      0u
#define WF_OFF        64u            // 8545 floats = 34180 B
#define PLANES_S_OFF  34304u        // 3*524288 u16 = 3145728 B
#define VOL_S_OFF     3180032u      // 2097152 u16  = 4194304 B
#define LINES_S_OFF   7374336u      // 12288 u16    = 24576 B
#define NEED_FAST     7398912u

// fp32 weight region (floats): Wf[3072] | bv[96] | W1t[5120] | b1v[128] | W2v[128] | b2v[1]

// =====================================================================
// dtype detect: count bf16-plausible exponents in first 64 u16s of coords
// =====================================================================
__global__ void kp_detect(const u16* __restrict__ cu, int* __restrict__ flag) {
    int t = threadIdx.x;            // 64 threads = 1 wave
    u16 v = cu[t];
    int e = (v >> 7) & 0xFF;
    bool inr = (e >= 90) && (e <= 126);
    unsigned long long m = __ballot(inr);
    if (t == 0) *flag = (__popcll(m) >= 56) ? 0 : 1;   // 0=bf16, 1=f32
}

// =====================================================================
// weights -> fp32 (W1 transposed to [128][40])
// =====================================================================
__global__ void kp_prep_weights(const void* __restrict__ Wx, const void* __restrict__ bx,
                                const void* __restrict__ Wy, const void* __restrict__ by,
                                const void* __restrict__ Wz, const void* __restrict__ bz,
                                const void* __restrict__ W1, const void* __restrict__ b1,
                                const void* __restrict__ W2, const void* __restrict__ b2,
                                float* __restrict__ wbase, const int* __restrict__ flag)
{
    int dt = *flag;
    float* Wf  = wbase;            // 3*1024
    float* bv  = Wf + 3072;        // 96
    float* W1t = bv + 96;          // 5120
    float* b1v = W1t + 5120;       // 128
    float* W2v = b1v + 128;        // 128
    float* b2v = W2v + 128;        // 1
    int t = blockIdx.x * blockDim.x + threadIdx.x;
    if (t < 3072) {
        int m = t >> 10, r = t & 1023;
        const void* s = (m == 0) ? Wx : (m == 1) ? Wy : Wz;
        Wf[t] = gld(dt, s, r);
    } else if (t < 3168) {
        int r = t - 3072;
        int m = r >> 5, c = r & 31;
        const void* s = (m == 0) ? bx : (m == 1) ? by : bz;
        bv[r] = gld(dt, s, c);
    } else if (t < 8288) {
        int r = t - 3168;                      // r = j*40+i
        int j = r / 40, i = r - j * 40;
        W1t[r] = gld(dt, W1, i * 128 + j);
    } else if (t < 8416) {
        b1v[t - 8288] = gld(dt, b1, t - 8288);
    } else if (t < 8544) {
        W2v[t - 8416] = gld(dt, W2, t - 8416);
    } else if (t == 8544) {
        b2v[0] = gld(dt, b2, 0);
    }
}

// =====================================================================
// grids -> bf16 channel-last, coalesced reads (pos-inner, 8 pos/thread)
// =====================================================================
__global__ void kp_prep_grids(const void* __restrict__ lx, const void* __restrict__ ly,
                              const void* __restrict__ lz,
                              const void* __restrict__ pxy, const void* __restrict__ pyz,
                              const void* __restrict__ pxz,
                              const void* __restrict__ vol,
                              u16* __restrict__ planes_s, u16* __restrict__ vol_s,
                              u16* __restrict__ lines_s, const int* __restrict__ flag)
{
    int dt = *flag;
    int t = blockIdx.x * blockDim.x + threadIdx.x;  // 1798*256 = 460288 exactly
    const void* src; int sidx; u16* dst; int dbase, dstride;
    if (t < 196608) {                 // planes: pl, c in [0,32), pb in [0,2048)
        int pl = t >> 16;             // /65536
        int r  = t & 65535;
        int c  = r >> 11, pb = r & 2047;
        src = (pl == 0) ? pxy : (pl == 1) ? pyz : pxz;
        sidx = c * 16384 + pb * 8;
        dst = planes_s;
        dbase = pl * 524288 + (pb * 8) * 32 + c;
        dstride = 32;
    } else if (t < 458752) {          // volume: c in [0,8), pb in [0,32768)
        int r = t - 196608;
        int c = r >> 15, pb = r & 32767;
        src = vol;
        sidx = c * 262144 + pb * 8;
        dst = vol_s;
        dbase = (pb * 8) * 8 + c;
        dstride = 8;
    } else {                          // lines: l, c in [0,32), pb in [0,16)
        int r = t - 458752;           // < 1536
        int l = r >> 9, rr = r & 511;
        int c = rr >> 4, pb = rr & 15;
        src = (l == 0) ? lx : (l == 1) ? ly : lz;
        sidx = c * 128 + pb * 8;
        dst = lines_s;
        dbase = l * 4096 + (pb * 8) * 32 + c;
        dstride = 32;
    }
    u16 o8[8];
    if (dt == 0) {
        u16x8 v = *(const u16x8*)((const u16*)src + sidx);
#pragma unroll
        for (int i = 0; i < 8; ++i) o8[i] = v[i];
    } else {
        const float* s = (const float*)src + sidx;
        f4 q0 = *(const f4*)s;
        f4 q1 = *(const f4*)(s + 4);
#pragma unroll
        for (int i = 0; i < 4; ++i) { o8[i] = f2bf(q0[i]); o8[4 + i] = f2bf(q1[i]); }
    }
#pragma unroll
    for (int i = 0; i < 8; ++i) dst[dbase + i * dstride] = o8[i];
}

// =====================================================================
// shared math
// =====================================================================
struct Samp { int i0, i1; float w0, w1; };

static __device__ __forceinline__ Samp make_samp(float g, int N) {
    float ix = (g + 1.0f) * 0.5f * (float)(N - 1);
    float fl = floorf(ix);
    float w  = ix - fl;
    int i  = (int)fl;
    int i1 = i + 1;
    float v0 = (i  >= 0 && i  < N) ? 1.0f : 0.0f;
    float v1 = (i1 >= 0 && i1 < N) ? 1.0f : 0.0f;
    Samp s;
    s.w0 = (1.0f - w) * v0;
    s.w1 = w * v1;
    s.i0 = min(max(i, 0), N - 1);
    s.i1 = min(max(i1, 0), N - 1);
    return s;
}

// fused term: feat[o] += phi_line[o] * phi_plane[o], shared W/b.
// Line data from LDS (channel-last), plane data bf16 channel-last global.
static __device__ __forceinline__ void term_fused(
    const u16* lline, const Samp& sl,
    const u16* __restrict__ Ps, const Samp& sa, const Samp& sb,
    const float* __restrict__ W, const float* __restrict__ b,
    float (&feat)[40])
{
    float ta[32], tb[32];
#pragma unroll
    for (int o = 0; o < 32; ++o) { ta[o] = b[o]; tb[o] = b[o]; }
    const u16x8* l0  = (const u16x8*)(lline + sl.i0 * 32);
    const u16x8* l1  = (const u16x8*)(lline + sl.i1 * 32);
    const u16x8* p00 = (const u16x8*)(Ps + (sb.i0 * 128 + sa.i0) * 32);
    const u16x8* p01 = (const u16x8*)(Ps + (sb.i0 * 128 + sa.i1) * 32);
    const u16x8* p10 = (const u16x8*)(Ps + (sb.i1 * 128 + sa.i0) * 32);
    const u16x8* p11 = (const u16x8*)(Ps + (sb.i1 * 128 + sa.i1) * 32);
    float w00 = sb.w0 * sa.w0, w01 = sb.w0 * sa.w1;
    float w10 = sb.w1 * sa.w0, w11 = sb.w1 * sa.w1;
#pragma unroll 2
    for (int cc = 0; cc < 4; ++cc) {
        u16x8 A0 = l0[cc], A1 = l1[cc];
        u16x8 Q00 = p00[cc], Q01 = p01[cc], Q10 = p10[cc], Q11 = p11[cc];
        const float* wr = W + cc * 256;
#pragma unroll
        for (int k = 0; k < 8; ++k) {
            float el = sl.w0 * bf2f(A0[k]) + sl.w1 * bf2f(A1[k]);
            float ep = w00 * bf2f(Q00[k]) + w01 * bf2f(Q01[k])
                     + w10 * bf2f(Q10[k]) + w11 * bf2f(Q11[k]);
            float r1 = fmaxf(el, 0.0f);
            float r2 = fmaxf(ep, 0.0f);
#pragma unroll
            for (int o = 0; o < 32; ++o) {
                float w = wr[k * 32 + o];
                ta[o] = fmaf(r1, w, ta[o]);
                tb[o] = fmaf(r2, w, tb[o]);
            }
        }
    }
#pragma unroll
    for (int o = 0; o < 32; ++o) feat[o] = fmaf(ta[o], tb[o], feat[o]);
}

static __device__ __forceinline__ float head_mlp(
    const float (&feat)[40], const float* __restrict__ W1t,
    const float* __restrict__ b1v, const float* __restrict__ W2v,
    const float* __restrict__ b2v)
{
    float acc_out = b2v[0];
#pragma unroll 2
    for (int j = 0; j < 128; ++j) {
        float acc = b1v[j];
        const float* wr = W1t + j * 40;
#pragma unroll
        for (int i = 0; i < 40; ++i)
            acc = fmaf(feat[i], wr[i], acc);
        acc_out = fmaf(fmaxf(acc, 0.0f), W2v[j], acc_out);
    }
    return acc_out;
}

// =====================================================================
// fast main: bf16 channel-last grids in ws, lines in LDS
// =====================================================================
__global__ __launch_bounds__(256) void kp_main_fast(
    const void* __restrict__ coords,
    const u16* __restrict__ planes_s, const u16* __restrict__ vol_s,
    const u16* __restrict__ lines_s,
    const float* __restrict__ wbase, const int* __restrict__ flag,
    void* __restrict__ out, int M)
{
    __shared__ __align__(16) u16 lline[12288];   // 24 KB: 3 lines channel-last
#pragma unroll
    for (int i = 0; i < 6; ++i) {
        int o = (i * 256 + threadIdx.x) * 8;
        *(u16x8*)(lline + o) = *(const u16x8*)(lines_s + o);
    }
    __syncthreads();

    int dt = *flag;
    const float* Wf  = wbase;
    const float* bv  = Wf + 3072;
    const float* W1t = bv + 96;
    const float* b1v = W1t + 5120;
    const float* W2v = b1v + 128;
    const float* b2v = W2v + 128;

    int p = blockIdx.x * 256 + threadIdx.x;
    p = min(p, M - 1);

    float x = gld(dt, coords, p * 3 + 0);
    float y = gld(dt, coords, p * 3 + 1);
    float z = gld(dt, coords, p * 3 + 2);

    Samp sx = make_samp(x, 128), sy = make_samp(y, 128), sz = make_samp(z, 128);

    float feat[40];
#pragma unroll
    for (int o = 0; o < 40; ++o) feat[o] = 0.0f;

    // volume first: loads issued early, each corner = one 16 B line-hit
    {
        Samp vx = make_samp(x, 64), vy = make_samp(y, 64), vz = make_samp(z, 64);
#pragma unroll
        for (int corner = 0; corner < 8; ++corner) {
            int dx = corner & 1, dy = (corner >> 1) & 1, dz = corner >> 2;
            int xi = dx ? vx.i1 : vx.i0;
            int yi = dy ? vy.i1 : vy.i0;
            int zi = dz ? vz.i1 : vz.i0;
            float w = (dx ? vx.w1 : vx.w0) * (dy ? vy.w1 : vy.w0) * (dz ? vz.w1 : vz.w0);
            u16x8 v = *(const u16x8*)(vol_s + (((zi * 64) + yi) * 64 + xi) * 8);
#pragma unroll
            for (int c = 0; c < 8; ++c)
                feat[32 + c] = fmaf(w, bf2f(v[c]), feat[32 + c]);
        }
    }

    // A: line_x & plane_yz(gx=y,gy=z) with Wx
    term_fused(lline + 0 * 4096, sx, planes_s + 1 * 524288, sy, sz, Wf + 0,    bv + 0,  feat);
    // B: line_y & plane_xz(gx=x,gy=z) with Wy
    term_fused(lline + 1 * 4096, sy, planes_s + 2 * 524288, sx, sz, Wf + 1024, bv + 32, feat);
    // C: line_z & plane_xy(gx=x,gy=y) with Wz
    term_fused(lline + 2 * 4096, sz, planes_s + 0 * 524288, sx, sy, Wf + 2048, bv + 64, feat);

    float r = head_mlp(feat, W1t, b1v, W2v, b2v);
    if (dt) ((float*)out)[p] = r;
    else    ((u16*)out)[p] = f2bf(r);
}

// =====================================================================
// direct fallback (ws too small): channel-major gathers, known-correct
// =====================================================================
static __device__ __forceinline__ void term_direct(
    int dt, const void* __restrict__ L, const Samp& sl,
    const void* __restrict__ P, const Samp& sa, const Samp& sb,
    const float* __restrict__ W, const float* __restrict__ b,
    float (&feat)[40])
{
    float ta[32], tb[32];
#pragma unroll
    for (int o = 0; o < 32; ++o) { ta[o] = b[o]; tb[o] = b[o]; }
    float w00 = sb.w0 * sa.w0, w01 = sb.w0 * sa.w1;
    float w10 = sb.w1 * sa.w0, w11 = sb.w1 * sa.w1;
    int i00 = sb.i0 * 128 + sa.i0, i01 = sb.i0 * 128 + sa.i1;
    int i10 = sb.i1 * 128 + sa.i0, i11 = sb.i1 * 128 + sa.i1;
#pragma unroll 1
    for (int c = 0; c < 32; ++c) {
        float el = sl.w0 * gld(dt, L, c * 128 + sl.i0)
                 + sl.w1 * gld(dt, L, c * 128 + sl.i1);
        float ep = w00 * gld(dt, P, c * 16384 + i00)
                 + w01 * gld(dt, P, c * 16384 + i01)
                 + w10 * gld(dt, P, c * 16384 + i10)
                 + w11 * gld(dt, P, c * 16384 + i11);
        float r1 = fmaxf(el, 0.0f);
        float r2 = fmaxf(ep, 0.0f);
        const float* wr = W + c * 32;
#pragma unroll
        for (int o = 0; o < 32; ++o) {
            float w = wr[o];
            ta[o] = fmaf(r1, w, ta[o]);
            tb[o] = fmaf(r2, w, tb[o]);
        }
    }
#pragma unroll
    for (int o = 0; o < 32; ++o) feat[o] = fmaf(ta[o], tb[o], feat[o]);
}

__global__ __launch_bounds__(256) void kp_main_direct(
    const void* __restrict__ coords,
    const void* __restrict__ lx, const void* __restrict__ ly, const void* __restrict__ lz,
    const void* __restrict__ pxy, const void* __restrict__ pyz, const void* __restrict__ pxz,
    const void* __restrict__ vol,
    const float* __restrict__ wbase, const int* __restrict__ flag,
    void* __restrict__ out, int M)
{
    int dt = *flag;
    const float* Wf  = wbase;
    const float* bv  = Wf + 3072;
    const float* W1t = bv + 96;
    const float* b1v = W1t + 5120;
    const float* W2v = b1v + 128;
    const float* b2v = W2v + 128;

    int p = blockIdx.x * 256 + threadIdx.x;
    p = min(p, M - 1);

    float x = gld(dt, coords, p * 3 + 0);
    float y = gld(dt, coords, p * 3 + 1);
    float z = gld(dt, coords, p * 3 + 2);

    Samp sx = make_samp(x, 128), sy = make_samp(y, 128), sz = make_samp(z, 128);

    float feat[40];
#pragma unroll
    for (int o = 0; o < 40; ++o) feat[o] = 0.0f;

    term_direct(dt, lx, sx, pyz, sy, sz, Wf + 0,    bv + 0,  feat);
    term_direct(dt, ly, sy, pxz, sx, sz, Wf + 1024, bv + 32, feat);
    term_direct(dt, lz, sz, pxy, sx, sy, Wf + 2048, bv + 64, feat);

    Samp vx = make_samp(x, 64), vy = make_samp(y, 64), vz = make_samp(z, 64);
#pragma unroll 1
    for (int corner = 0; corner < 8; ++corner) {
        int dx = corner & 1, dy = (corner >> 1) & 1, dz = corner >> 2;
        int xi = dx ? vx.i1 : vx.i0;
        int yi = dy ? vy.i1 : vy.i0;
        int zi = dz ? vz.i1 : vz.i0;
        float w = (dx ? vx.w1 : vx.w0) * (dy ? vy.w1 : vy.w0) * (dz ? vz.w1 : vz.w0);
        int pos = ((zi * 64) + yi) * 64 + xi;
#pragma unroll
        for (int c = 0; c < 8; ++c)
            feat[32 + c] = fmaf(w, gld(dt, vol, c * 262144 + pos), feat[32 + c]);
    }

    float r = head_mlp(feat, W1t, b1v, W2v, b2v);
    if (dt) ((float*)out)[p] = r;
    else    ((u16*)out)[p] = f2bf(r);
}

// =====================================================================
extern "C" void kernel_launch(void* const* d_in, const int* in_sizes, int n_in,
                              void* d_out, int out_size, void* d_ws, size_t ws_size,
                              hipStream_t stream) {
    const void* coords = d_in[0];
    const void* lx  = d_in[1];
    const void* ly  = d_in[2];
    const void* lz  = d_in[3];
    const void* pxy = d_in[4];
    const void* pyz = d_in[5];
    const void* pxz = d_in[6];
    const void* vol = d_in[7];
    const void* Wx  = d_in[8];
    const void* bx  = d_in[9];
    const void* Wy  = d_in[10];
    const void* by  = d_in[11];
    const void* Wz  = d_in[12];
    const void* bz  = d_in[13];
    const void* W1  = d_in[14];
    const void* b1  = d_in[15];
    const void* W2  = d_in[16];
    const void* b2  = d_in[17];

    int M = in_sizes[0] / 3;

    char* ws = (char*)d_ws;
    int*   flag     = (int*)(ws + FLAG_OFF);
    float* wbase    = (float*)(ws + WF_OFF);
    u16*   planes_s = (u16*)(ws + PLANES_S_OFF);
    u16*   vol_s    = (u16*)(ws + VOL_S_OFF);
    u16*   lines_s  = (u16*)(ws + LINES_S_OFF);

    kp_detect<<<1, 64, 0, stream>>>((const u16*)coords, flag);
    kp_prep_weights<<<34, 256, 0, stream>>>(Wx, bx, Wy, by, Wz, bz, W1, b1, W2, b2,
                                            wbase, flag);

    int blocks = (M + 255) / 256;
    if (ws_size >= (size_t)NEED_FAST) {
        kp_prep_grids<<<1798, 256, 0, stream>>>(lx, ly, lz, pxy, pyz, pxz, vol,
                                                planes_s, vol_s, lines_s, flag);
        kp_main_fast<<<blocks, 256, 0, stream>>>(coords, planes_s, vol_s, lines_s,
                                                 wbase, flag, d_out, M);
    } else {
        kp_main_direct<<<blocks, 256, 0, stream>>>(coords, lx, ly, lz, pxy, pyz, pxz,
                                                   vol, wbase, flag, d_out, M);
    }
}

// Round 4
// 400.270 us; speedup vs baseline: 1.7519x; 1.7519x over previous
//
#include <hip/hip_runtime.h>

typedef unsigned short u16;
typedef float f4 __attribute__((ext_vector_type(4)));
typedef u16 u16x8 __attribute__((ext_vector_type(8)));

// ---------- bf16 helpers ----------
static __device__ __forceinline__ float bf2f(u16 u) {
    union { unsigned int i; float f; } v;
    v.i = ((unsigned int)u) << 16;
    return v.f;
}
static __device__ __forceinline__ u16 f2bf(float f) {
    union { float f; unsigned int i; } v;
    v.f = f;
    unsigned int x = v.i;
    x += 0x7fffu + ((x >> 16) & 1u);   // RNE
    return (u16)(x >> 16);
}
// dtype-flexible load: dt==0 -> bf16, dt==1 -> f32
static __device__ __forceinline__ float gld(int dt, const void* p, int i) {
    return dt ? ((const float*)p)[i] : bf2f(((const u16*)p)[i]);
}

// ---------- ws layout (bytes) ----------
#define FLAG_OFF      0u
#define WF_OFF        64u            // 8545 floats
#define PLANES_S_OFF  34304u         // 3*524288 u16 = 3145728 B
#define VOL_S_OFF     3180032u       // 2097152 u16  = 4194304 B
#define LINES_S_OFF   7374336u       // 12288 u16    = 24576 B
#define HIST_OFF      7398912u       // 4096 u32
#define OFFS_OFF      7415296u       // 4096 u32
#define ORDER_OFF     7431680u       // 4*M
#define NEED_DIRECT_ONLY 0u

#define NBUCK 4096

// =====================================================================
// dtype detect
// =====================================================================
__global__ void kp_detect(const u16* __restrict__ cu, int* __restrict__ flag) {
    int t = threadIdx.x;            // 64 threads = 1 wave
    u16 v = cu[t];
    int e = (v >> 7) & 0xFF;
    bool inr = (e >= 90) && (e <= 126);
    unsigned long long m = __ballot(inr);
    if (t == 0) *flag = (__popcll(m) >= 56) ? 0 : 1;   // 0=bf16, 1=f32
}

// =====================================================================
// weights -> fp32 (W1 transposed to [128][40])
// =====================================================================
__global__ void kp_prep_weights(const void* __restrict__ Wx, const void* __restrict__ bx,
                                const void* __restrict__ Wy, const void* __restrict__ by,
                                const void* __restrict__ Wz, const void* __restrict__ bz,
                                const void* __restrict__ W1, const void* __restrict__ b1,
                                const void* __restrict__ W2, const void* __restrict__ b2,
                                float* __restrict__ wbase, const int* __restrict__ flag)
{
    int dt = *flag;
    float* Wf  = wbase;            // 3*1024
    float* bv  = Wf + 3072;        // 96
    float* W1t = bv + 96;          // 5120
    float* b1v = W1t + 5120;       // 128
    float* W2v = b1v + 128;        // 128
    float* b2v = W2v + 128;        // 1
    int t = blockIdx.x * blockDim.x + threadIdx.x;
    if (t < 3072) {
        int m = t >> 10, r = t & 1023;
        const void* s = (m == 0) ? Wx : (m == 1) ? Wy : Wz;
        Wf[t] = gld(dt, s, r);
    } else if (t < 3168) {
        int r = t - 3072;
        int m = r >> 5, c = r & 31;
        const void* s = (m == 0) ? bx : (m == 1) ? by : bz;
        bv[r] = gld(dt, s, c);
    } else if (t < 8288) {
        int r = t - 3168;                      // r = j*40+i
        int j = r / 40, i = r - j * 40;
        W1t[r] = gld(dt, W1, i * 128 + j);
    } else if (t < 8416) {
        b1v[t - 8288] = gld(dt, b1, t - 8288);
    } else if (t < 8544) {
        W2v[t - 8416] = gld(dt, W2, t - 8416);
    } else if (t == 8544) {
        b2v[0] = gld(dt, b2, 0);
    }
}

// =====================================================================
// grids -> bf16 channel-last, coalesced reads
// =====================================================================
__global__ void kp_prep_grids(const void* __restrict__ lx, const void* __restrict__ ly,
                              const void* __restrict__ lz,
                              const void* __restrict__ pxy, const void* __restrict__ pyz,
                              const void* __restrict__ pxz,
                              const void* __restrict__ vol,
                              u16* __restrict__ planes_s, u16* __restrict__ vol_s,
                              u16* __restrict__ lines_s, const int* __restrict__ flag)
{
    int dt = *flag;
    int t = blockIdx.x * blockDim.x + threadIdx.x;  // 1798*256 = 460288 exactly
    const void* src; int sidx; u16* dst; int dbase, dstride;
    if (t < 196608) {                 // planes
        int pl = t >> 16;
        int r  = t & 65535;
        int c  = r >> 11, pb = r & 2047;
        src = (pl == 0) ? pxy : (pl == 1) ? pyz : pxz;
        sidx = c * 16384 + pb * 8;
        dst = planes_s;
        dbase = pl * 524288 + (pb * 8) * 32 + c;
        dstride = 32;
    } else if (t < 458752) {          // volume
        int r = t - 196608;
        int c = r >> 15, pb = r & 32767;
        src = vol;
        sidx = c * 262144 + pb * 8;
        dst = vol_s;
        dbase = (pb * 8) * 8 + c;
        dstride = 8;
    } else {                          // lines
        int r = t - 458752;           // < 1536
        int l = r >> 9, rr = r & 511;
        int c = rr >> 4, pb = rr & 15;
        src = (l == 0) ? lx : (l == 1) ? ly : lz;
        sidx = c * 128 + pb * 8;
        dst = lines_s;
        dbase = l * 4096 + (pb * 8) * 32 + c;
        dstride = 32;
    }
    u16 o8[8];
    if (dt == 0) {
        u16x8 v = *(const u16x8*)((const u16*)src + sidx);
#pragma unroll
        for (int i = 0; i < 8; ++i) o8[i] = v[i];
    } else {
        const float* s = (const float*)src + sidx;
        f4 q0 = *(const f4*)s;
        f4 q1 = *(const f4*)(s + 4);
#pragma unroll
        for (int i = 0; i < 4; ++i) { o8[i] = f2bf(q0[i]); o8[4 + i] = f2bf(q1[i]); }
    }
#pragma unroll
    for (int i = 0; i < 8; ++i) dst[dbase + i * dstride] = o8[i];
}

// =====================================================================
// spatial counting sort: key = 16x16x16 bucket
// =====================================================================
static __device__ __forceinline__ int make_key(int dt, const void* coords, int p) {
    float x = gld(dt, coords, p * 3 + 0);
    float y = gld(dt, coords, p * 3 + 1);
    float z = gld(dt, coords, p * 3 + 2);
    int kx = min(max((int)((x + 1.0f) * 8.0f), 0), 15);
    int ky = min(max((int)((y + 1.0f) * 8.0f), 0), 15);
    int kz = min(max((int)((z + 1.0f) * 8.0f), 0), 15);
    return (kz * 16 + ky) * 16 + kx;
}

__global__ void kp_zero_hist(unsigned int* __restrict__ hist) {
    int t = blockIdx.x * blockDim.x + threadIdx.x;
    if (t < 2 * NBUCK) hist[t] = 0u;   // hist + offs contiguous
}

__global__ __launch_bounds__(256) void kp_hist(
    const void* __restrict__ coords, const int* __restrict__ flag,
    unsigned int* __restrict__ hist, int M)
{
    __shared__ unsigned int lh[NBUCK];
    int dt = *flag;
    for (int i = threadIdx.x; i < NBUCK; i += 256) lh[i] = 0u;
    __syncthreads();
    int stride = gridDim.x * 256;
    for (int p = blockIdx.x * 256 + threadIdx.x; p < M; p += stride)
        atomicAdd(&lh[make_key(dt, coords, p)], 1u);
    __syncthreads();
    for (int i = threadIdx.x; i < NBUCK; i += 256) {
        unsigned int v = lh[i];
        if (v) atomicAdd(&hist[i], v);
    }
}

__global__ __launch_bounds__(256) void kp_scan(
    const unsigned int* __restrict__ hist, unsigned int* __restrict__ offs)
{
    __shared__ unsigned int part[256];
    int t = threadIdx.x;
    unsigned int s = 0;
#pragma unroll
    for (int i = 0; i < 16; ++i) s += hist[t * 16 + i];
    part[t] = s;
    __syncthreads();
    if (t == 0) {
        unsigned int run = 0;
        for (int i = 0; i < 256; ++i) { unsigned int v = part[i]; part[i] = run; run += v; }
    }
    __syncthreads();
    unsigned int run = part[t];
#pragma unroll
    for (int i = 0; i < 16; ++i) { offs[t * 16 + i] = run; run += hist[t * 16 + i]; }
}

__global__ __launch_bounds__(256) void kp_scatter(
    const void* __restrict__ coords, const int* __restrict__ flag,
    unsigned int* __restrict__ offs, int* __restrict__ order, int M)
{
    int dt = *flag;
    int stride = gridDim.x * 256;
    for (int p = blockIdx.x * 256 + threadIdx.x; p < M; p += stride) {
        int key = make_key(dt, coords, p);
        unsigned int pos = atomicAdd(&offs[key], 1u);
        order[pos] = p;
    }
}

// =====================================================================
// shared math
// =====================================================================
struct Samp { int i0, i1; float w0, w1; };

static __device__ __forceinline__ Samp make_samp(float g, int N) {
    float ix = (g + 1.0f) * 0.5f * (float)(N - 1);
    float fl = floorf(ix);
    float w  = ix - fl;
    int i  = (int)fl;
    int i1 = i + 1;
    float v0 = (i  >= 0 && i  < N) ? 1.0f : 0.0f;
    float v1 = (i1 >= 0 && i1 < N) ? 1.0f : 0.0f;
    Samp s;
    s.w0 = (1.0f - w) * v0;
    s.w1 = w * v1;
    s.i0 = min(max(i, 0), N - 1);
    s.i1 = min(max(i1, 0), N - 1);
    return s;
}

// fused term: feat[o] += phi_line[o] * phi_plane[o], shared W/b.
static __device__ __forceinline__ void term_fused(
    const u16* lline, const Samp& sl,
    const u16* __restrict__ Ps, const Samp& sa, const Samp& sb,
    const float* __restrict__ W, const float* __restrict__ b,
    float (&feat)[40])
{
    float ta[32], tb[32];
#pragma unroll
    for (int o = 0; o < 32; ++o) { ta[o] = b[o]; tb[o] = b[o]; }
    const u16x8* l0  = (const u16x8*)(lline + sl.i0 * 32);
    const u16x8* l1  = (const u16x8*)(lline + sl.i1 * 32);
    const u16x8* p00 = (const u16x8*)(Ps + (sb.i0 * 128 + sa.i0) * 32);
    const u16x8* p01 = (const u16x8*)(Ps + (sb.i0 * 128 + sa.i1) * 32);
    const u16x8* p10 = (const u16x8*)(Ps + (sb.i1 * 128 + sa.i0) * 32);
    const u16x8* p11 = (const u16x8*)(Ps + (sb.i1 * 128 + sa.i1) * 32);
    float w00 = sb.w0 * sa.w0, w01 = sb.w0 * sa.w1;
    float w10 = sb.w1 * sa.w0, w11 = sb.w1 * sa.w1;
#pragma unroll 1
    for (int cc = 0; cc < 4; ++cc) {
        u16x8 A0 = l0[cc], A1 = l1[cc];
        u16x8 Q00 = p00[cc], Q01 = p01[cc], Q10 = p10[cc], Q11 = p11[cc];
        const float* wr = W + cc * 256;
#pragma unroll
        for (int k = 0; k < 8; ++k) {
            float el = sl.w0 * bf2f(A0[k]) + sl.w1 * bf2f(A1[k]);
            float ep = w00 * bf2f(Q00[k]) + w01 * bf2f(Q01[k])
                     + w10 * bf2f(Q10[k]) + w11 * bf2f(Q11[k]);
            float r1 = fmaxf(el, 0.0f);
            float r2 = fmaxf(ep, 0.0f);
#pragma unroll
            for (int o = 0; o < 32; ++o) {
                float w = wr[k * 32 + o];
                ta[o] = fmaf(r1, w, ta[o]);
                tb[o] = fmaf(r2, w, tb[o]);
            }
        }
    }
#pragma unroll
    for (int o = 0; o < 32; ++o) feat[o] = fmaf(ta[o], tb[o], feat[o]);
}

static __device__ __forceinline__ float head_mlp(
    const float (&feat)[40], const float* __restrict__ W1t,
    const float* __restrict__ b1v, const float* __restrict__ W2v,
    const float* __restrict__ b2v)
{
    float acc_out = b2v[0];
#pragma unroll 2
    for (int j = 0; j < 128; ++j) {
        float acc = b1v[j];
        const float* wr = W1t + j * 40;
#pragma unroll
        for (int i = 0; i < 40; ++i)
            acc = fmaf(feat[i], wr[i], acc);
        acc_out = fmaf(fmaxf(acc, 0.0f), W2v[j], acc_out);
    }
    return acc_out;
}

// =====================================================================
// sorted main: bf16 channel-last grids, lines in LDS, spatially-ordered pts
// =====================================================================
__global__ __launch_bounds__(256) void kp_main_sorted(
    const void* __restrict__ coords, const int* __restrict__ order,
    const u16* __restrict__ planes_s, const u16* __restrict__ vol_s,
    const u16* __restrict__ lines_s,
    const float* __restrict__ wbase, const int* __restrict__ flag,
    void* __restrict__ out, int M)
{
    __shared__ __align__(16) u16 lline[12288];   // 24 KB: 3 lines channel-last
#pragma unroll
    for (int i = 0; i < 6; ++i) {
        int o = (i * 256 + threadIdx.x) * 8;
        *(u16x8*)(lline + o) = *(const u16x8*)(lines_s + o);
    }
    __syncthreads();

    int dt = *flag;
    const float* Wf  = wbase;
    const float* bv  = Wf + 3072;
    const float* W1t = bv + 96;
    const float* b1v = W1t + 5120;
    const float* W2v = b1v + 128;
    const float* b2v = W2v + 128;

    int p = blockIdx.x * 256 + threadIdx.x;
    p = min(p, M - 1);
    int sp = order[p];

    float x = gld(dt, coords, sp * 3 + 0);
    float y = gld(dt, coords, sp * 3 + 1);
    float z = gld(dt, coords, sp * 3 + 2);

    Samp sx = make_samp(x, 128), sy = make_samp(y, 128), sz = make_samp(z, 128);

    float feat[40];
#pragma unroll
    for (int o = 0; o < 40; ++o) feat[o] = 0.0f;

    // A: line_x & plane_yz(gx=y,gy=z) with Wx
    term_fused(lline + 0 * 4096, sx, planes_s + 1 * 524288, sy, sz, Wf + 0,    bv + 0,  feat);
    // B: line_y & plane_xz(gx=x,gy=z) with Wy
    term_fused(lline + 1 * 4096, sy, planes_s + 2 * 524288, sx, sz, Wf + 1024, bv + 32, feat);
    // C: line_z & plane_xy(gx=x,gy=y) with Wz
    term_fused(lline + 2 * 4096, sz, planes_s + 0 * 524288, sx, sy, Wf + 2048, bv + 64, feat);

    // volume
    {
        Samp vx = make_samp(x, 64), vy = make_samp(y, 64), vz = make_samp(z, 64);
#pragma unroll
        for (int corner = 0; corner < 8; ++corner) {
            int dx = corner & 1, dy = (corner >> 1) & 1, dz = corner >> 2;
            int xi = dx ? vx.i1 : vx.i0;
            int yi = dy ? vy.i1 : vy.i0;
            int zi = dz ? vz.i1 : vz.i0;
            float w = (dx ? vx.w1 : vx.w0) * (dy ? vy.w1 : vy.w0) * (dz ? vz.w1 : vz.w0);
            u16x8 v = *(const u16x8*)(vol_s + (((zi * 64) + yi) * 64 + xi) * 8);
#pragma unroll
            for (int c = 0; c < 8; ++c)
                feat[32 + c] = fmaf(w, bf2f(v[c]), feat[32 + c]);
        }
    }

    float r = head_mlp(feat, W1t, b1v, W2v, b2v);
    if (dt) ((float*)out)[sp] = r;
    else    ((u16*)out)[sp] = f2bf(r);
}

// =====================================================================
// direct fallback (ws too small): channel-major gathers, known-correct
// =====================================================================
static __device__ __forceinline__ void term_direct(
    int dt, const void* __restrict__ L, const Samp& sl,
    const void* __restrict__ P, const Samp& sa, const Samp& sb,
    const float* __restrict__ W, const float* __restrict__ b,
    float (&feat)[40])
{
    float ta[32], tb[32];
#pragma unroll
    for (int o = 0; o < 32; ++o) { ta[o] = b[o]; tb[o] = b[o]; }
    float w00 = sb.w0 * sa.w0, w01 = sb.w0 * sa.w1;
    float w10 = sb.w1 * sa.w0, w11 = sb.w1 * sa.w1;
    int i00 = sb.i0 * 128 + sa.i0, i01 = sb.i0 * 128 + sa.i1;
    int i10 = sb.i1 * 128 + sa.i0, i11 = sb.i1 * 128 + sa.i1;
#pragma unroll 1
    for (int c = 0; c < 32; ++c) {
        float el = sl.w0 * gld(dt, L, c * 128 + sl.i0)
                 + sl.w1 * gld(dt, L, c * 128 + sl.i1);
        float ep = w00 * gld(dt, P, c * 16384 + i00)
                 + w01 * gld(dt, P, c * 16384 + i01)
                 + w10 * gld(dt, P, c * 16384 + i10)
                 + w11 * gld(dt, P, c * 16384 + i11);
        float r1 = fmaxf(el, 0.0f);
        float r2 = fmaxf(ep, 0.0f);
        const float* wr = W + c * 32;
#pragma unroll
        for (int o = 0; o < 32; ++o) {
            float w = wr[o];
            ta[o] = fmaf(r1, w, ta[o]);
            tb[o] = fmaf(r2, w, tb[o]);
        }
    }
#pragma unroll
    for (int o = 0; o < 32; ++o) feat[o] = fmaf(ta[o], tb[o], feat[o]);
}

__global__ __launch_bounds__(256) void kp_main_direct(
    const void* __restrict__ coords,
    const void* __restrict__ lx, const void* __restrict__ ly, const void* __restrict__ lz,
    const void* __restrict__ pxy, const void* __restrict__ pyz, const void* __restrict__ pxz,
    const void* __restrict__ vol,
    const float* __restrict__ wbase, const int* __restrict__ flag,
    void* __restrict__ out, int M)
{
    int dt = *flag;
    const float* Wf  = wbase;
    const float* bv  = Wf + 3072;
    const float* W1t = bv + 96;
    const float* b1v = W1t + 5120;
    const float* W2v = b1v + 128;
    const float* b2v = W2v + 128;

    int p = blockIdx.x * 256 + threadIdx.x;
    p = min(p, M - 1);

    float x = gld(dt, coords, p * 3 + 0);
    float y = gld(dt, coords, p * 3 + 1);
    float z = gld(dt, coords, p * 3 + 2);

    Samp sx = make_samp(x, 128), sy = make_samp(y, 128), sz = make_samp(z, 128);

    float feat[40];
#pragma unroll
    for (int o = 0; o < 40; ++o) feat[o] = 0.0f;

    term_direct(dt, lx, sx, pyz, sy, sz, Wf + 0,    bv + 0,  feat);
    term_direct(dt, ly, sy, pxz, sx, sz, Wf + 1024, bv + 32, feat);
    term_direct(dt, lz, sz, pxy, sx, sy, Wf + 2048, bv + 64, feat);

    Samp vx = make_samp(x, 64), vy = make_samp(y, 64), vz = make_samp(z, 64);
#pragma unroll 1
    for (int corner = 0; corner < 8; ++corner) {
        int dx = corner & 1, dy = (corner >> 1) & 1, dz = corner >> 2;
        int xi = dx ? vx.i1 : vx.i0;
        int yi = dy ? vy.i1 : vy.i0;
        int zi = dz ? vz.i1 : vz.i0;
        float w = (dx ? vx.w1 : vx.w0) * (dy ? vy.w1 : vy.w0) * (dz ? vz.w1 : vz.w0);
        int pos = ((zi * 64) + yi) * 64 + xi;
#pragma unroll
        for (int c = 0; c < 8; ++c)
            feat[32 + c] = fmaf(w, gld(dt, vol, c * 262144 + pos), feat[32 + c]);
    }

    float r = head_mlp(feat, W1t, b1v, W2v, b2v);
    if (dt) ((float*)out)[p] = r;
    else    ((u16*)out)[p] = f2bf(r);
}

// =====================================================================
extern "C" void kernel_launch(void* const* d_in, const int* in_sizes, int n_in,
                              void* d_out, int out_size, void* d_ws, size_t ws_size,
                              hipStream_t stream) {
    const void* coords = d_in[0];
    const void* lx  = d_in[1];
    const void* ly  = d_in[2];
    const void* lz  = d_in[3];
    const void* pxy = d_in[4];
    const void* pyz = d_in[5];
    const void* pxz = d_in[6];
    const void* vol = d_in[7];
    const void* Wx  = d_in[8];
    const void* bx  = d_in[9];
    const void* Wy  = d_in[10];
    const void* by  = d_in[11];
    const void* Wz  = d_in[12];
    const void* bz  = d_in[13];
    const void* W1  = d_in[14];
    const void* b1  = d_in[15];
    const void* W2  = d_in[16];
    const void* b2  = d_in[17];

    int M = in_sizes[0] / 3;

    char* ws = (char*)d_ws;
    int*          flag     = (int*)(ws + FLAG_OFF);
    float*        wbase    = (float*)(ws + WF_OFF);
    u16*          planes_s = (u16*)(ws + PLANES_S_OFF);
    u16*          vol_s    = (u16*)(ws + VOL_S_OFF);
    u16*          lines_s  = (u16*)(ws + LINES_S_OFF);
    unsigned int* hist     = (unsigned int*)(ws + HIST_OFF);
    unsigned int* offs     = (unsigned int*)(ws + OFFS_OFF);
    int*          order    = (int*)(ws + ORDER_OFF);

    size_t need_sorted = (size_t)ORDER_OFF + (size_t)M * 4u;

    kp_detect<<<1, 64, 0, stream>>>((const u16*)coords, flag);
    kp_prep_weights<<<34, 256, 0, stream>>>(Wx, bx, Wy, by, Wz, bz, W1, b1, W2, b2,
                                            wbase, flag);

    int blocks = (M + 255) / 256;
    if (ws_size >= need_sorted) {
        kp_prep_grids<<<1798, 256, 0, stream>>>(lx, ly, lz, pxy, pyz, pxz, vol,
                                                planes_s, vol_s, lines_s, flag);
        kp_zero_hist<<<32, 256, 0, stream>>>(hist);
        kp_hist<<<480, 256, 0, stream>>>(coords, flag, hist, M);
        kp_scan<<<1, 256, 0, stream>>>(hist, offs);
        kp_scatter<<<480, 256, 0, stream>>>(coords, flag, offs, order, M);
        kp_main_sorted<<<blocks, 256, 0, stream>>>(coords, order, planes_s, vol_s,
                                                   lines_s, wbase, flag, d_out, M);
    } else {
        kp_main_direct<<<blocks, 256, 0, stream>>>(coords, lx, ly, lz, pxy, pyz, pxz,
                                                   vol, wbase, flag, d_out, M);
    }
}

// Round 6
// 312.600 us; speedup vs baseline: 2.2432x; 1.2805x over previous
//
#include <hip/hip_runtime.h>

typedef unsigned short u16;
typedef float f4 __attribute__((ext_vector_type(4)));
typedef u16 u16x8 __attribute__((ext_vector_type(8)));
typedef _Float16 half2 __attribute__((ext_vector_type(2)));

// ---------- bf16 helpers ----------
static __device__ __forceinline__ float bf2f(u16 u) {
    union { unsigned int i; float f; } v;
    v.i = ((unsigned int)u) << 16;
    return v.f;
}
static __device__ __forceinline__ u16 f2bf(float f) {
    union { float f; unsigned int i; } v;
    v.f = f;
    unsigned int x = v.i;
    x += 0x7fffu + ((x >> 16) & 1u);   // RNE
    return (u16)(x >> 16);
}
// dtype-flexible load: dt==0 -> bf16, dt==1 -> f32
static __device__ __forceinline__ float gld(int dt, const void* p, int i) {
    return dt ? ((const float*)p)[i] : bf2f(((const u16*)p)[i]);
}

// f16 pair dot: full-rate v_dot2_f32_f16 when available
#if __has_builtin(__builtin_amdgcn_fdot2)
static __device__ __forceinline__ float FDOT2(half2 a, half2 b, float c) {
    return __builtin_amdgcn_fdot2(a, b, c, false);
}
#else
static __device__ __forceinline__ float FDOT2(half2 a, half2 b, float c) {
    return fmaf((float)a[0], (float)b[0], fmaf((float)a[1], (float)b[1], c));
}
#endif
static __device__ __forceinline__ half2 pk(float a, float b) {
    return __builtin_bit_cast(half2, __builtin_amdgcn_cvt_pkrtz(a, b));
}

// ---------- ws layout (bytes) ----------
#define FLAG_OFF      0u
#define WF_OFF        64u            // 4449 u32 = 17796 B
#define PLANES_S_OFF  34304u         // 3*524288 u16 = 3145728 B
#define VOL_S_OFF     3180032u       // 2097152 u16  = 4194304 B
#define LINES_S_OFF   7374336u       // 12288 u16    = 24576 B
#define HIST_OFF      7398912u       // 4096 u32
#define OFFS_OFF      7415296u       // 4096 u32
#define ORDER_OFF     7431680u       // 4*M

#define NBUCK 4096

// weight region (4-byte units):
//   Wph[3*512] h2 | bv[96] f32 | W1ph[2560] h2 | b1v[128] | W2v[128] | b2v[1]

// =====================================================================
// dtype detect
// =====================================================================
__global__ void kp_detect(const u16* __restrict__ cu, int* __restrict__ flag) {
    int t = threadIdx.x;            // 64 threads = 1 wave
    u16 v = cu[t];
    int e = (v >> 7) & 0xFF;
    bool inr = (e >= 90) && (e <= 126);
    unsigned long long m = __ballot(inr);
    if (t == 0) *flag = (__popcll(m) >= 56) ? 0 : 1;   // 0=bf16, 1=f32
}

// =====================================================================
// weights -> packed f16 pairs (matvec W, W1t) + f32 biases
// =====================================================================
__global__ void kp_prep_weights(const void* __restrict__ Wx, const void* __restrict__ bx,
                                const void* __restrict__ Wy, const void* __restrict__ by,
                                const void* __restrict__ Wz, const void* __restrict__ bz,
                                const void* __restrict__ W1, const void* __restrict__ b1,
                                const void* __restrict__ W2, const void* __restrict__ b2,
                                float* __restrict__ wbase, const int* __restrict__ flag)
{
    int dt = *flag;
    half2* Wph  = (half2*)wbase;            // 1536: [3][16 kp][32 o]
    float* bv   = wbase + 1536;             // 96
    half2* W1ph = (half2*)(wbase + 1632);   // 2560: [128 j][20 ip]
    float* b1v  = wbase + 4192;             // 128
    float* W2v  = wbase + 4320;             // 128
    float* b2v  = wbase + 4448;             // 1
    int t = blockIdx.x * blockDim.x + threadIdx.x;
    if (t < 1536) {
        int m = t >> 9, idx = t & 511;
        int kp = idx >> 5, o = idx & 31;
        const void* s = (m == 0) ? Wx : (m == 1) ? Wy : Wz;
        float f0 = gld(dt, s, (2 * kp) * 32 + o);
        float f1 = gld(dt, s, (2 * kp + 1) * 32 + o);
        Wph[t] = pk(f0, f1);
    } else if (t < 1632) {
        int r = t - 1536;
        int m = r >> 5, c = r & 31;
        const void* s = (m == 0) ? bx : (m == 1) ? by : bz;
        bv[r] = gld(dt, s, c);
    } else if (t < 4192) {
        int r = t - 1632;                      // r = j*20+ip
        int j = r / 20, ip = r - j * 20;
        float f0 = gld(dt, W1, (2 * ip) * 128 + j);
        float f1 = gld(dt, W1, (2 * ip + 1) * 128 + j);
        W1ph[r] = pk(f0, f1);
    } else if (t < 4320) {
        b1v[t - 4192] = gld(dt, b1, t - 4192);
    } else if (t < 4448) {
        W2v[t - 4320] = gld(dt, W2, t - 4320);
    } else if (t == 4448) {
        b2v[0] = gld(dt, b2, 0);
    }
}

// =====================================================================
// grids -> bf16 channel-last; WRITE-coalesced (16B/lane), gather reads
// =====================================================================
__global__ void kp_prep_grids(const void* __restrict__ lx, const void* __restrict__ ly,
                              const void* __restrict__ lz,
                              const void* __restrict__ pxy, const void* __restrict__ pyz,
                              const void* __restrict__ pxz,
                              const void* __restrict__ vol,
                              u16* __restrict__ planes_s, u16* __restrict__ vol_s,
                              u16* __restrict__ lines_s, const int* __restrict__ flag)
{
    int dt = *flag;
    int t = blockIdx.x * blockDim.x + threadIdx.x;  // 1798*256 = 460288 exactly
    u16x8 v;
    if (t < 196608) {                 // planes: 8 consecutive out u16
        int o = t * 8;
        int pl = o >> 19;
        int r  = o & 524287;
        int pos = r >> 5, c0 = r & 31;        // c0 in {0,8,16,24}
        const void* src = (pl == 0) ? pxy : (pl == 1) ? pyz : pxz;
#pragma unroll
        for (int i = 0; i < 8; ++i)
            v[i] = dt ? f2bf(((const float*)src)[(c0 + i) * 16384 + pos])
                      : ((const u16*)src)[(c0 + i) * 16384 + pos];
        *(u16x8*)(planes_s + o) = v;
    } else if (t < 458752) {          // volume: thread = one pos, 8 channels
        int pos = t - 196608;         // < 262144
#pragma unroll
        for (int c = 0; c < 8; ++c)
            v[c] = dt ? f2bf(((const float*)vol)[c * 262144 + pos])
                      : ((const u16*)vol)[c * 262144 + pos];
        *(u16x8*)(vol_s + pos * 8) = v;
    } else {                          // lines
        int o = (t - 458752) * 8;     // < 12288
        int l = o >> 12, rr = o & 4095;
        int pos = rr >> 5, c0 = rr & 31;
        const void* src = (l == 0) ? lx : (l == 1) ? ly : lz;
#pragma unroll
        for (int i = 0; i < 8; ++i)
            v[i] = dt ? f2bf(((const float*)src)[(c0 + i) * 128 + pos])
                      : ((const u16*)src)[(c0 + i) * 128 + pos];
        *(u16x8*)(lines_s + o) = v;
    }
}

// =====================================================================
// spatial counting sort: key = 16x16x16 bucket
// =====================================================================
static __device__ __forceinline__ int make_key(int dt, const void* coords, int p) {
    float x = gld(dt, coords, p * 3 + 0);
    float y = gld(dt, coords, p * 3 + 1);
    float z = gld(dt, coords, p * 3 + 2);
    int kx = min(max((int)((x + 1.0f) * 8.0f), 0), 15);
    int ky = min(max((int)((y + 1.0f) * 8.0f), 0), 15);
    int kz = min(max((int)((z + 1.0f) * 8.0f), 0), 15);
    return (kz * 16 + ky) * 16 + kx;
}

__global__ void kp_zero_hist(unsigned int* __restrict__ hist) {
    int t = blockIdx.x * blockDim.x + threadIdx.x;
    if (t < 2 * NBUCK) hist[t] = 0u;   // hist + offs contiguous
}

__global__ __launch_bounds__(256) void kp_hist(
    const void* __restrict__ coords, const int* __restrict__ flag,
    unsigned int* __restrict__ hist, int M)
{
    __shared__ unsigned int lh[NBUCK];
    int dt = *flag;
    for (int i = threadIdx.x; i < NBUCK; i += 256) lh[i] = 0u;
    __syncthreads();
    int stride = gridDim.x * 256;
    for (int p = blockIdx.x * 256 + threadIdx.x; p < M; p += stride)
        atomicAdd(&lh[make_key(dt, coords, p)], 1u);
    __syncthreads();
    for (int i = threadIdx.x; i < NBUCK; i += 256) {
        unsigned int v = lh[i];
        if (v) atomicAdd(&hist[i], v);
    }
}

__global__ __launch_bounds__(256) void kp_scan(
    const unsigned int* __restrict__ hist, unsigned int* __restrict__ offs)
{
    __shared__ unsigned int part[256];
    int t = threadIdx.x;
    unsigned int s = 0;
#pragma unroll
    for (int i = 0; i < 16; ++i) s += hist[t * 16 + i];
    part[t] = s;
    __syncthreads();
    if (t == 0) {
        unsigned int run = 0;
        for (int i = 0; i < 256; ++i) { unsigned int v = part[i]; part[i] = run; run += v; }
    }
    __syncthreads();
    unsigned int run = part[t];
#pragma unroll
    for (int i = 0; i < 16; ++i) { offs[t * 16 + i] = run; run += hist[t * 16 + i]; }
}

__global__ __launch_bounds__(256) void kp_scatter(
    const void* __restrict__ coords, const int* __restrict__ flag,
    unsigned int* __restrict__ offs, int* __restrict__ order, int M)
{
    int dt = *flag;
    int stride = gridDim.x * 256;
    for (int p = blockIdx.x * 256 + threadIdx.x; p < M; p += stride) {
        int key = make_key(dt, coords, p);
        unsigned int pos = atomicAdd(&offs[key], 1u);
        order[pos] = p;
    }
}

// =====================================================================
// shared math
// =====================================================================
struct Samp { int i0, i1; float w0, w1; };

static __device__ __forceinline__ Samp make_samp(float g, int N) {
    float ix = (g + 1.0f) * 0.5f * (float)(N - 1);
    float fl = floorf(ix);
    float w  = ix - fl;
    int i  = (int)fl;
    int i1 = i + 1;
    float v0 = (i  >= 0 && i  < N) ? 1.0f : 0.0f;
    float v1 = (i1 >= 0 && i1 < N) ? 1.0f : 0.0f;
    Samp s;
    s.w0 = (1.0f - w) * v0;
    s.w1 = w * v1;
    s.i0 = min(max(i, 0), N - 1);
    s.i1 = min(max(i1, 0), N - 1);
    return s;
}

// fused term with f16 dot2: feat[o] += phi_line[o] * phi_plane[o]
static __device__ __forceinline__ void term_fused(
    const u16* lline, const Samp& sl,
    const u16* __restrict__ Ps, const Samp& sa, const Samp& sb,
    const half2* __restrict__ Wp, const float* __restrict__ b,
    float (&feat)[40])
{
    float ta[32], tb[32];
#pragma unroll
    for (int o = 0; o < 32; ++o) { ta[o] = b[o]; tb[o] = b[o]; }
    const u16x8* l0  = (const u16x8*)(lline + sl.i0 * 32);
    const u16x8* l1  = (const u16x8*)(lline + sl.i1 * 32);
    const u16x8* p00 = (const u16x8*)(Ps + (sb.i0 * 128 + sa.i0) * 32);
    const u16x8* p01 = (const u16x8*)(Ps + (sb.i0 * 128 + sa.i1) * 32);
    const u16x8* p10 = (const u16x8*)(Ps + (sb.i1 * 128 + sa.i0) * 32);
    const u16x8* p11 = (const u16x8*)(Ps + (sb.i1 * 128 + sa.i1) * 32);
    float w00 = sb.w0 * sa.w0, w01 = sb.w0 * sa.w1;
    float w10 = sb.w1 * sa.w0, w11 = sb.w1 * sa.w1;
#pragma unroll 1
    for (int cc = 0; cc < 4; ++cc) {
        u16x8 A0 = l0[cc], A1 = l1[cc];
        u16x8 Q00 = p00[cc], Q01 = p01[cc], Q10 = p10[cc], Q11 = p11[cc];
#pragma unroll
        for (int kk = 0; kk < 4; ++kk) {
            int k0 = 2 * kk, k1 = 2 * kk + 1;
            float el0 = sl.w0 * bf2f(A0[k0]) + sl.w1 * bf2f(A1[k0]);
            float el1 = sl.w0 * bf2f(A0[k1]) + sl.w1 * bf2f(A1[k1]);
            float ep0 = w00 * bf2f(Q00[k0]) + w01 * bf2f(Q01[k0])
                      + w10 * bf2f(Q10[k0]) + w11 * bf2f(Q11[k0]);
            float ep1 = w00 * bf2f(Q00[k1]) + w01 * bf2f(Q01[k1])
                      + w10 * bf2f(Q10[k1]) + w11 * bf2f(Q11[k1]);
            half2 r1 = pk(fmaxf(el0, 0.0f), fmaxf(el1, 0.0f));
            half2 r2 = pk(fmaxf(ep0, 0.0f), fmaxf(ep1, 0.0f));
            const half2* wr = Wp + (cc * 4 + kk) * 32;
#pragma unroll
            for (int o = 0; o < 32; ++o) {
                half2 w = wr[o];
                ta[o] = FDOT2(r1, w, ta[o]);
                tb[o] = FDOT2(r2, w, tb[o]);
            }
        }
    }
#pragma unroll
    for (int o = 0; o < 32; ++o) feat[o] = fmaf(ta[o], tb[o], feat[o]);
}

static __device__ __forceinline__ float head_mlp(
    const float (&feat)[40], const half2* __restrict__ W1ph,
    const float* __restrict__ b1v, const float* __restrict__ W2v,
    const float* __restrict__ b2v)
{
    half2 fp[20];
#pragma unroll
    for (int ip = 0; ip < 20; ++ip) fp[ip] = pk(feat[2 * ip], feat[2 * ip + 1]);
    float acc_out = b2v[0];
#pragma unroll 2
    for (int j = 0; j < 128; ++j) {
        float acc = b1v[j];
        const half2* wr = W1ph + j * 20;
#pragma unroll
        for (int ip = 0; ip < 20; ++ip)
            acc = FDOT2(fp[ip], wr[ip], acc);
        acc_out = fmaf(fmaxf(acc, 0.0f), W2v[j], acc_out);
    }
    return acc_out;
}

// =====================================================================
// sorted main: bf16 channel-last grids, lines in LDS, spatially-ordered pts
// =====================================================================
__global__ __launch_bounds__(256) void kp_main_sorted(
    const void* __restrict__ coords, const int* __restrict__ order,
    const u16* __restrict__ planes_s, const u16* __restrict__ vol_s,
    const u16* __restrict__ lines_s,
    const float* __restrict__ wbase, const int* __restrict__ flag,
    void* __restrict__ out, int M)
{
    __shared__ __align__(16) u16 lline[12288];   // 24 KB: 3 lines channel-last
#pragma unroll
    for (int i = 0; i < 6; ++i) {
        int o = (i * 256 + threadIdx.x) * 8;
        *(u16x8*)(lline + o) = *(const u16x8*)(lines_s + o);
    }
    __syncthreads();

    int dt = *flag;
    const half2* Wph  = (const half2*)wbase;
    const float* bv   = wbase + 1536;
    const half2* W1ph = (const half2*)(wbase + 1632);
    const float* b1v  = wbase + 4192;
    const float* W2v  = wbase + 4320;
    const float* b2v  = wbase + 4448;

    int p = blockIdx.x * 256 + threadIdx.x;
    p = min(p, M - 1);
    int sp = order[p];

    float x = gld(dt, coords, sp * 3 + 0);
    float y = gld(dt, coords, sp * 3 + 1);
    float z = gld(dt, coords, sp * 3 + 2);

    Samp sx = make_samp(x, 128), sy = make_samp(y, 128), sz = make_samp(z, 128);

    float feat[40];
#pragma unroll
    for (int o = 0; o < 40; ++o) feat[o] = 0.0f;

    // A: line_x & plane_yz(gx=y,gy=z) with Wx
    term_fused(lline + 0 * 4096, sx, planes_s + 1 * 524288, sy, sz, Wph + 0,    bv + 0,  feat);
    // B: line_y & plane_xz(gx=x,gy=z) with Wy
    term_fused(lline + 1 * 4096, sy, planes_s + 2 * 524288, sx, sz, Wph + 512,  bv + 32, feat);
    // C: line_z & plane_xy(gx=x,gy=y) with Wz
    term_fused(lline + 2 * 4096, sz, planes_s + 0 * 524288, sx, sy, Wph + 1024, bv + 64, feat);

    // volume
    {
        Samp vx = make_samp(x, 64), vy = make_samp(y, 64), vz = make_samp(z, 64);
#pragma unroll
        for (int corner = 0; corner < 8; ++corner) {
            int dx = corner & 1, dy = (corner >> 1) & 1, dz = corner >> 2;
            int xi = dx ? vx.i1 : vx.i0;
            int yi = dy ? vy.i1 : vy.i0;
            int zi = dz ? vz.i1 : vz.i0;
            float w = (dx ? vx.w1 : vx.w0) * (dy ? vy.w1 : vy.w0) * (dz ? vz.w1 : vz.w0);
            u16x8 v = *(const u16x8*)(vol_s + (((zi * 64) + yi) * 64 + xi) * 8);
#pragma unroll
            for (int c = 0; c < 8; ++c)
                feat[32 + c] = fmaf(w, bf2f(v[c]), feat[32 + c]);
        }
    }

    float r = head_mlp(feat, W1ph, b1v, W2v, b2v);
    if (dt) ((float*)out)[sp] = r;
    else    ((u16*)out)[sp] = f2bf(r);
}

// =====================================================================
// direct fallback (ws too small): channel-major gathers
// =====================================================================
static __device__ __forceinline__ void term_direct(
    int dt, const void* __restrict__ L, const Samp& sl,
    const void* __restrict__ P, const Samp& sa, const Samp& sb,
    const half2* __restrict__ Wp, const float* __restrict__ b,
    float (&feat)[40])
{
    float ta[32], tb[32];
#pragma unroll
    for (int o = 0; o < 32; ++o) { ta[o] = b[o]; tb[o] = b[o]; }
    float w00 = sb.w0 * sa.w0, w01 = sb.w0 * sa.w1;
    float w10 = sb.w1 * sa.w0, w11 = sb.w1 * sa.w1;
    int i00 = sb.i0 * 128 + sa.i0, i01 = sb.i0 * 128 + sa.i1;
    int i10 = sb.i1 * 128 + sa.i0, i11 = sb.i1 * 128 + sa.i1;
#pragma unroll 1
    for (int kp = 0; kp < 16; ++kp) {
        int c0 = 2 * kp, c1 = 2 * kp + 1;
        float el0 = sl.w0 * gld(dt, L, c0 * 128 + sl.i0) + sl.w1 * gld(dt, L, c0 * 128 + sl.i1);
        float el1 = sl.w0 * gld(dt, L, c1 * 128 + sl.i0) + sl.w1 * gld(dt, L, c1 * 128 + sl.i1);
        float ep0 = w00 * gld(dt, P, c0 * 16384 + i00) + w01 * gld(dt, P, c0 * 16384 + i01)
                  + w10 * gld(dt, P, c0 * 16384 + i10) + w11 * gld(dt, P, c0 * 16384 + i11);
        float ep1 = w00 * gld(dt, P, c1 * 16384 + i00) + w01 * gld(dt, P, c1 * 16384 + i01)
                  + w10 * gld(dt, P, c1 * 16384 + i10) + w11 * gld(dt, P, c1 * 16384 + i11);
        half2 r1 = pk(fmaxf(el0, 0.0f), fmaxf(el1, 0.0f));
        half2 r2 = pk(fmaxf(ep0, 0.0f), fmaxf(ep1, 0.0f));
        const half2* wr = Wp + kp * 32;
#pragma unroll
        for (int o = 0; o < 32; ++o) {
            half2 w = wr[o];
            ta[o] = FDOT2(r1, w, ta[o]);
            tb[o] = FDOT2(r2, w, tb[o]);
        }
    }
#pragma unroll
    for (int o = 0; o < 32; ++o) feat[o] = fmaf(ta[o], tb[o], feat[o]);
}

__global__ __launch_bounds__(256) void kp_main_direct(
    const void* __restrict__ coords,
    const void* __restrict__ lx, const void* __restrict__ ly, const void* __restrict__ lz,
    const void* __restrict__ pxy, const void* __restrict__ pyz, const void* __restrict__ pxz,
    const void* __restrict__ vol,
    const float* __restrict__ wbase, const int* __restrict__ flag,
    void* __restrict__ out, int M)
{
    int dt = *flag;
    const half2* Wph  = (const half2*)wbase;
    const float* bv   = wbase + 1536;
    const half2* W1ph = (const half2*)(wbase + 1632);
    const float* b1v  = wbase + 4192;
    const float* W2v  = wbase + 4320;
    const float* b2v  = wbase + 4448;

    int p = blockIdx.x * 256 + threadIdx.x;
    p = min(p, M - 1);

    float x = gld(dt, coords, p * 3 + 0);
    float y = gld(dt, coords, p * 3 + 1);
    float z = gld(dt, coords, p * 3 + 2);

    Samp sx = make_samp(x, 128), sy = make_samp(y, 128), sz = make_samp(z, 128);

    float feat[40];
#pragma unroll
    for (int o = 0; o < 40; ++o) feat[o] = 0.0f;

    term_direct(dt, lx, sx, pyz, sy, sz, Wph + 0,    bv + 0,  feat);
    term_direct(dt, ly, sy, pxz, sx, sz, Wph + 512,  bv + 32, feat);
    term_direct(dt, lz, sz, pxy, sx, sy, Wph + 1024, bv + 64, feat);

    Samp vx = make_samp(x, 64), vy = make_samp(y, 64), vz = make_samp(z, 64);
#pragma unroll 1
    for (int corner = 0; corner < 8; ++corner) {
        int dx = corner & 1, dy = (corner >> 1) & 1, dz = corner >> 2;
        int xi = dx ? vx.i1 : vx.i0;
        int yi = dy ? vy.i1 : vy.i0;
        int zi = dz ? vz.i1 : vz.i0;
        float w = (dx ? vx.w1 : vx.w0) * (dy ? vy.w1 : vy.w0) * (dz ? vz.w1 : vz.w0);
        int pos = ((zi * 64) + yi) * 64 + xi;
#pragma unroll
        for (int c = 0; c < 8; ++c)
            feat[32 + c] = fmaf(w, gld(dt, vol, c * 262144 + pos), feat[32 + c]);
    }

    float r = head_mlp(feat, W1ph, b1v, W2v, b2v);
    if (dt) ((float*)out)[p] = r;
    else    ((u16*)out)[p] = f2bf(r);
}

// =====================================================================
extern "C" void kernel_launch(void* const* d_in, const int* in_sizes, int n_in,
                              void* d_out, int out_size, void* d_ws, size_t ws_size,
                              hipStream_t stream) {
    const void* coords = d_in[0];
    const void* lx  = d_in[1];
    const void* ly  = d_in[2];
    const void* lz  = d_in[3];
    const void* pxy = d_in[4];
    const void* pyz = d_in[5];
    const void* pxz = d_in[6];
    const void* vol = d_in[7];
    const void* Wx  = d_in[8];
    const void* bx  = d_in[9];
    const void* Wy  = d_in[10];
    const void* by  = d_in[11];
    const void* Wz  = d_in[12];
    const void* bz  = d_in[13];
    const void* W1  = d_in[14];
    const void* b1  = d_in[15];
    const void* W2  = d_in[16];
    const void* b2  = d_in[17];

    int M = in_sizes[0] / 3;

    char* ws = (char*)d_ws;
    int*          flag     = (int*)(ws + FLAG_OFF);
    float*        wbase    = (float*)(ws + WF_OFF);
    u16*          planes_s = (u16*)(ws + PLANES_S_OFF);
    u16*          vol_s    = (u16*)(ws + VOL_S_OFF);
    u16*          lines_s  = (u16*)(ws + LINES_S_OFF);
    unsigned int* hist     = (unsigned int*)(ws + HIST_OFF);
    unsigned int* offs     = (unsigned int*)(ws + OFFS_OFF);
    int*          order    = (int*)(ws + ORDER_OFF);

    size_t need_sorted = (size_t)ORDER_OFF + (size_t)M * 4u;

    kp_detect<<<1, 64, 0, stream>>>((const u16*)coords, flag);
    kp_prep_weights<<<18, 256, 0, stream>>>(Wx, bx, Wy, by, Wz, bz, W1, b1, W2, b2,
                                            wbase, flag);

    int blocks = (M + 255) / 256;
    if (ws_size >= need_sorted) {
        kp_prep_grids<<<1798, 256, 0, stream>>>(lx, ly, lz, pxy, pyz, pxz, vol,
                                                planes_s, vol_s, lines_s, flag);
        kp_zero_hist<<<32, 256, 0, stream>>>(hist);
        kp_hist<<<480, 256, 0, stream>>>(coords, flag, hist, M);
        kp_scan<<<1, 256, 0, stream>>>(hist, offs);
        kp_scatter<<<480, 256, 0, stream>>>(coords, flag, offs, order, M);
        kp_main_sorted<<<blocks, 256, 0, stream>>>(coords, order, planes_s, vol_s,
                                                   lines_s, wbase, flag, d_out, M);
    } else {
        kp_main_direct<<<blocks, 256, 0, stream>>>(coords, lx, ly, lz, pxy, pyz, pxz,
                                                   vol, wbase, flag, d_out, M);
    }
}